// Round 15
// baseline (93.351 us; speedup 1.0000x reference)
//
#include <hip/hip_runtime.h>

// Fused causal attention head: B=8, T=2048, C=1024, H=128 (fp32 in/out).
//   q,k,v = x@W{q,k,v};  out = softmax(tril(q k^T * C^-0.5)) @ v
// All intermediates (Wtf, Qf, Kf, Vf) are MFMA-fragment-major so every hot load
// is a coalesced `base + lane*16B` read (round-6 win).
//   QK-frag layout: frag(t16, k32) = 1KB contiguous;
//     idx(t,h) = ((t>>4)*NK + (h>>5))*512 + ((h>>3)&3)*128 + (t&15)*8 + (h&7)
//   V-frag layout: frag(t16, h16) = 512B contiguous.
// Round-15: revert to round-13 structure (best, 69.3; rounds 9-14 showed proj
//   ~40us is this structure's floor for a (16K x 384 x 1K) GEMM — matches the
//   guide's shape-curve for m97-class kernels). One change: attn prefetches
//   the ENTIRE V-tile (32 x 8B regs) right after the S^T cluster, so the
//   24 V-loads formerly inline in the PV MFMA cluster (3 exposed L2-latency
//   stalls per kv-tile) hide under LOADK+mask+softmax. launch_bounds(512,2)
//   guarantees the 256-VGPR budget (est. ~232, no spill).
// Workspace (~13 MB): [0,768K) Wtf  [1M,5M) Qf  [5M,9M) Kf  [9M,13M) Vf

#define B_ 8
#define T_ 2048
#define C_ 1024
#define H_ 128

typedef __attribute__((ext_vector_type(4))) float  f32x4;
typedef __attribute__((ext_vector_type(8))) __bf16 bf16x8;
typedef __attribute__((ext_vector_type(4))) __bf16 bf16x4;
typedef __attribute__((ext_vector_type(4))) short  short4v;

#define QSCALE (0.03125f * 1.44269504088896340736f)  // C^-0.5 * log2(e)

static __device__ __forceinline__ short f2bf(float f) {
  union { __bf16 b; short s; } u;
  u.b = (__bf16)f;
  return u.s;
}

static __device__ __forceinline__ unsigned packbf2(float lo, float hi) {
  union { __bf16 b; unsigned short s; } a, c;
  a.b = (__bf16)lo; c.b = (__bf16)hi;
  return (unsigned)a.s | ((unsigned)c.s << 16);
}

// fragment-major index helpers
static __device__ __forceinline__ size_t qk_idx(int t, int h, int nk) {
  return ((size_t)((t >> 4) * nk + (h >> 5)) << 9) + (((h >> 3) & 3) << 7)
       + ((t & 15) << 3) + (h & 7);
}
static __device__ __forceinline__ size_t v_idx(int h, int t) {
  return ((size_t)((t >> 4) * 8 + (h >> 4)) << 8) + ((h & 15) << 4) + (t & 15);
}

// D = A(16x16) * B(16x16) + C, bf16, K=16.
static __device__ __forceinline__ f32x4 mfma16(unsigned a0, unsigned a1,
                                               unsigned b0, unsigned b1, f32x4 c) {
#if __has_builtin(__builtin_amdgcn_mfma_f32_16x16x16_bf16)
  union { unsigned u[2]; bf16x4 v; } ua, ub;
  ua.u[0] = a0; ua.u[1] = a1; ub.u[0] = b0; ub.u[1] = b1;
  return __builtin_amdgcn_mfma_f32_16x16x16_bf16(ua.v, ub.v, c, 0, 0, 0);
#elif __has_builtin(__builtin_amdgcn_mfma_f32_16x16x16bf16_1k)
  union { unsigned u[2]; short4v v; } ua, ub;
  ua.u[0] = a0; ua.u[1] = a1; ub.u[0] = b0; ub.u[1] = b1;
  return __builtin_amdgcn_mfma_f32_16x16x16bf16_1k(ua.v, ub.v, c, 0, 0, 0);
#else
  union { unsigned u[2]; short4v v; } ua, ub;
  ua.u[0] = a0; ua.u[1] = a1; ub.u[0] = b0; ub.u[1] = b1;
  f32x4 d = c;
  asm volatile("v_mfma_f32_16x16x16_bf16 %0, %1, %2, %0"
               : "+v"(d) : "v"(ua.v), "v"(ub.v));
  return d;
#endif
}

// ---------------- prep: Wtf frag-major; Wq pre-scaled by QSCALE -------------------
__global__ void prep_wt(const float* __restrict__ Wq, const float* __restrict__ Wk,
                        const float* __restrict__ Wv, short* __restrict__ Wtf) {
  __shared__ float L[64 * 129];
  const int mtx = blockIdx.x >> 4, kc = blockIdx.x & 15;
  const int k0 = kc * 64;
  const float* W = (mtx == 0) ? Wq : (mtx == 1 ? Wk : Wv);
  const float s = (mtx == 0) ? QSCALE : 1.0f;
  for (int i = threadIdx.x; i < 64 * 128; i += 256) {
    int kk = i >> 7, c = i & 127;
    L[kk * 129 + c] = W[(size_t)(k0 + kk) * H_ + c] * s;
  }
  __syncthreads();
  for (int i = threadIdx.x; i < 128 * 64; i += 256) {
    int n = i >> 6, kk = i & 63;
    Wtf[qk_idx(mtx * 128 + n, k0 + kk, 32)] = f2bf(L[kk * 129 + n]);
  }
}

// ---------------- proj: BM=64 x BN=192, BK=128, raw-barrier pipeline, grid 512 ----
// (round-13 structure, unchanged)
__global__ __launch_bounds__(256) void proj(const float* __restrict__ x,
                                            const short* __restrict__ Wtf,
                                            short* __restrict__ Qf,
                                            short* __restrict__ Kf,
                                            short* __restrict__ Vf) {
  __shared__ __align__(16) short At[2][64 * 128];  // bf16 tiles, 16 KB each
  const int tid = threadIdx.x, lane = tid & 63, wv = tid >> 6;
  const int cg = lane & 15, rg = lane >> 4;
  const int lane8 = lane << 3;
  const int g = (blockIdx.x & 7) * 64 + (blockIdx.x >> 3);
  const int mb = g >> 1, bn = g & 1;
  const int m0 = mb * 64;
  const int nfrag0 = bn * 12 + wv * 3;
  const float* xblk = x + (size_t)m0 * C_;

  f32x4 acc[4][3];
#pragma unroll
  for (int i = 0; i < 4; ++i)
#pragma unroll
    for (int j = 0; j < 3; ++j) {
      f32x4 z = {0.f, 0.f, 0.f, 0.f};
      acc[i][j] = z;
    }

  f32x4 ldr[4][2];  // staging regs: 8 dwordx4 loads/thread (one kt tile)

#define PLOAD(kt)                                                              \
  { _Pragma("unroll") for (int it = 0; it < 4; ++it) {                         \
      int ls = it * 256 + tid; int r = ls >> 4, sc = ls & 15;                  \
      const float* p = xblk + (size_t)r * C_ + (kt) * 128 + sc * 8;            \
      ldr[it][0] = *(const f32x4*)p; ldr[it][1] = *(const f32x4*)(p + 4);      \
  } }

#define PWRITE(bf)                                                             \
  { _Pragma("unroll") for (int it = 0; it < 4; ++it) {                         \
      int ls = it * 256 + tid; int r = ls >> 4, sc = ls & 15;                  \
      bf16x8 tv;                                                               \
      tv[0] = (__bf16)ldr[it][0][0]; tv[1] = (__bf16)ldr[it][0][1];            \
      tv[2] = (__bf16)ldr[it][0][2]; tv[3] = (__bf16)ldr[it][0][3];            \
      tv[4] = (__bf16)ldr[it][1][0]; tv[5] = (__bf16)ldr[it][1][1];            \
      tv[6] = (__bf16)ldr[it][1][2]; tv[7] = (__bf16)ldr[it][1][3];            \
      *(bf16x8*)&At[bf][r * 128 + ((sc ^ (r & 7)) << 3)] = tv;                 \
  } }

  // raw barrier: ds-writes visible (lgkmcnt 0) but vector loads STAY in flight
#define RAWBAR()                                                               \
  { asm volatile("s_waitcnt lgkmcnt(0)" ::: "memory");                         \
    __builtin_amdgcn_sched_barrier(0);                                         \
    __builtin_amdgcn_s_barrier(); }

  PLOAD(0);
  PWRITE(0);
  PLOAD(1);
  RAWBAR();

  for (int kt = 0; kt < 8; ++kt) {
    const int cur = kt & 1;

#pragma unroll
    for (int ks = 0; ks < 4; ++ks) {
      bf16x8 af[4];
#pragma unroll
      for (int fm = 0; fm < 4; ++fm) {
        int r = fm * 16 + cg;
        int slot = (ks * 4 + rg) ^ (r & 7);
        af[fm] = *(const bf16x8*)&At[cur][r * 128 + (slot << 3)];
      }
#pragma unroll
      for (int nf = 0; nf < 3; ++nf) {
        bf16x8 bfr = *(const bf16x8*)&Wtf[((size_t)((nfrag0 + nf) * 32 + kt * 4 + ks) << 9) + lane8];
#pragma unroll
        for (int fm = 0; fm < 4; ++fm)
          acc[fm][nf] = __builtin_amdgcn_mfma_f32_16x16x32_bf16(af[fm], bfr, acc[fm][nf], 0, 0, 0);
      }
    }
    if (kt < 7) PWRITE(cur ^ 1);
    if (kt < 6) PLOAD(kt + 2);
    RAWBAR();
  }
#undef PLOAD
#undef PWRITE
#undef RAWBAR

  // epilogue: D frag row=(lane>>4)*4+r, col=lane&15; scatter into frag layouts
#pragma unroll
  for (int fm = 0; fm < 4; ++fm) {
#pragma unroll
    for (int nf = 0; nf < 3; ++nf) {
      int n = (nfrag0 + nf) * 16 + cg;
      int rowm = m0 + fm * 16 + rg * 4;
      size_t boff = (size_t)(rowm >> 11) << 18;   // batch * 2048*128
      f32x4 v = acc[fm][nf];
      if (n < 128) {
#pragma unroll
        for (int r = 0; r < 4; ++r)
          Qf[boff + qk_idx((rowm + r) & 2047, n, 4)] = f2bf(v[r]);
      } else if (n < 256) {
#pragma unroll
        for (int r = 0; r < 4; ++r)
          Kf[boff + qk_idx((rowm + r) & 2047, n - 128, 4)] = f2bf(v[r]);
      } else {
#pragma unroll
        for (int r = 0; r < 4; ++r)
          Vf[boff + v_idx(n - 256, (rowm + r) & 2047)] = f2bf(v[r]);
      }
    }
  }
}

// ---------------- attn: paired q-groups, per-SIMD balanced, full-V prefetch -------
// grid 256: b = bid&7 (XCD-local K/V), p = bid>>3 in [0,32).
// 8 waves: wv 0-3 -> qg = 63-p (kv-split 4), wv 4-7 -> qg = p (kv-split 4).
#define OCW 132  // 128 + 4 pad
__global__ __launch_bounds__(512, 2) void attn(const short* __restrict__ Qf,
                                               const short* __restrict__ Kf,
                                               const short* __restrict__ Vf,
                                               float* __restrict__ out) {
  __shared__ __align__(16) float OC[4][32 * OCW];   // 67.6 KB, reused hi then lo
  __shared__ float Mml[8][32], Lml[8][32];
  const int tid = threadIdx.x, lane = tid & 63, wv = tid >> 6;
  const int cg = lane & 15, rg = lane >> 4;
  const int lane8 = lane << 3;
  const int bid = blockIdx.x;
  const int b = bid & 7;
  const int p = bid >> 3;                // 0..31
  const int grp = wv >> 2;               // 0 = hi group, 1 = lo group
  const int wvl = wv & 3;                // kv-split index within group
  const int qg = grp ? p : (63 - p);
  const int q0 = qg << 5;
  const int NT = (q0 + 95) >> 6;         // ceil((q0+32)/64) kv-tiles of 64
  const int SPW = (NT + 3) >> 2;
  const int t0 = wvl * SPW;
  const int t1 = (t0 + SPW < NT) ? (t0 + SPW) : NT;

  const short* Qp = Qf + ((size_t)b << 18);
  const short* Kp = Kf + ((size_t)b << 18);
  const short* Vp = Vf + ((size_t)b << 18);
  const float NEG_INF = -__builtin_inff();

  // Q frags (B-operand for swapped QK^T): coalesced frag reads
  bf16x8 qf[2][4];
#pragma unroll
  for (int qc = 0; qc < 2; ++qc)
#pragma unroll
    for (int ks = 0; ks < 4; ++ks)
      qf[qc][ks] = *(const bf16x8*)&Qp[((size_t)(((q0 >> 4) + qc) * 4 + ks) << 9) + lane8];

  f32x4 o[8][2];                         // O^T: o[hf][qc][r] = O[q][h=hf*16+rg*4+r]
#pragma unroll
  for (int f = 0; f < 8; ++f)
#pragma unroll
    for (int qc = 0; qc < 2; ++qc) { f32x4 z = {0.f, 0.f, 0.f, 0.f}; o[f][qc] = z; }
  float m[2] = {NEG_INF, NEG_INF}, lsum[2] = {0.0f, 0.0f};

  bf16x8 kf[4][4];
#define LOADK(t_)                                                              \
  { const short* ktp = Kp + (size_t)(t_) * 8192;                               \
    _Pragma("unroll") for (int nf_ = 0; nf_ < 4; ++nf_)                        \
    _Pragma("unroll") for (int ks_ = 0; ks_ < 4; ++ks_)                        \
      kf[nf_][ks_] = *(const bf16x8*)&ktp[((nf_ * 4 + ks_) << 9) + lane8]; }

  if (t0 < t1) LOADK(t0);

  for (int t = t0; t < t1; ++t) {
    const int kv0 = t * 64;
    const short* vtile = Vp + (size_t)t * 8192;

    f32x4 s[4][2];
#pragma unroll
    for (int nf = 0; nf < 4; ++nf)
#pragma unroll
      for (int qc = 0; qc < 2; ++qc) { f32x4 z = {0.f, 0.f, 0.f, 0.f}; s[nf][qc] = z; }

    // S^T = K Q^T
    __builtin_amdgcn_s_setprio(1);
#pragma unroll
    for (int nf = 0; nf < 4; ++nf)
#pragma unroll
      for (int ks = 0; ks < 4; ++ks) {
        s[nf][0] = __builtin_amdgcn_mfma_f32_16x16x32_bf16(kf[nf][ks], qf[0][ks], s[nf][0], 0, 0, 0);
        s[nf][1] = __builtin_amdgcn_mfma_f32_16x16x32_bf16(kf[nf][ks], qf[1][ks], s[nf][1], 0, 0, 0);
      }
    __builtin_amdgcn_s_setprio(0);

    // FULL V-tile prefetch (32 x 8B): latency hides under LOADK+mask+softmax
    unsigned va[4][8], vb[4][8];
#pragma unroll
    for (int nf = 0; nf < 4; ++nf)
#pragma unroll
      for (int hf = 0; hf < 8; ++hf) {
        const unsigned* vp = (const unsigned*)&vtile[((nf * 8 + hf) << 8) + (cg << 4) + (rg << 2)];
        va[nf][hf] = vp[0]; vb[nf][hf] = vp[1];
      }

    // K software-pipeline: next tile into the same kf regs
    if (t + 1 < t1) LOADK(t + 1);

    // causal mask (only the globally-last tile straddles the diagonal)
    if (t == NT - 1) {
#pragma unroll
      for (int nf = 0; nf < 4; ++nf)
#pragma unroll
        for (int qc = 0; qc < 2; ++qc)
#pragma unroll
          for (int r = 0; r < 4; ++r)
            if (kv0 + nf * 16 + rg * 4 + r > q0 + qc * 16 + cg) s[nf][qc][r] = NEG_INF;
    }

    // online softmax (exp2 domain) with T13 defer-max
    unsigned pk[4][2][2];
#pragma unroll
    for (int qc = 0; qc < 2; ++qc) {
      float pm = s[0][qc][0];
#pragma unroll
      for (int nf = 0; nf < 4; ++nf)
#pragma unroll
        for (int r = 0; r < 4; ++r) pm = fmaxf(pm, s[nf][qc][r]);
      pm = fmaxf(pm, __shfl_xor(pm, 16));
      pm = fmaxf(pm, __shfl_xor(pm, 32));   // full row max
      if (!__all(pm <= m[qc] + 8.0f)) {     // T13: rescale only on real growth
        float mn = fmaxf(m[qc], pm);
        float sf = exp2f(m[qc] - mn);       // first tile: exp2(-inf) = 0
        m[qc] = mn;
        lsum[qc] *= sf;
#pragma unroll
        for (int f = 0; f < 8; ++f)
#pragma unroll
          for (int r = 0; r < 4; ++r) o[f][qc][r] *= sf;
      }
      float mq = m[qc];
#pragma unroll
      for (int nf = 0; nf < 4; ++nf) {
        float p0 = exp2f(s[nf][qc][0] - mq), p1 = exp2f(s[nf][qc][1] - mq);
        float p2 = exp2f(s[nf][qc][2] - mq), p3 = exp2f(s[nf][qc][3] - mq);
        lsum[qc] += (p0 + p1) + (p2 + p3);
        pk[nf][qc][0] = packbf2(p0, p1);
        pk[nf][qc][1] = packbf2(p2, p3);
      }
    }

    // O^T += V^T P^T via 16x16x16 — all operands in registers
    __builtin_amdgcn_s_setprio(1);
#pragma unroll
    for (int nf = 0; nf < 4; ++nf) {
      const unsigned b00 = pk[nf][0][0], b01 = pk[nf][0][1];
      const unsigned b10 = pk[nf][1][0], b11 = pk[nf][1][1];
#pragma unroll
      for (int hf = 0; hf < 8; ++hf) {
        o[hf][0] = mfma16(va[nf][hf], vb[nf][hf], b00, b01, o[hf][0]);
        o[hf][1] = mfma16(va[nf][hf], vb[nf][hf], b10, b11, o[hf][1]);
      }
    }
    __builtin_amdgcn_s_setprio(0);
  }
#undef LOADK

  // reduce l across rg groups (same q); m already row-uniform
#pragma unroll
  for (int qc = 0; qc < 2; ++qc) {
    lsum[qc] += __shfl_xor(lsum[qc], 16);
    lsum[qc] += __shfl_xor(lsum[qc], 32);
  }
  if (lane < 16) {
#pragma unroll
    for (int qc = 0; qc < 2; ++qc) {
      Mml[wv][qc * 16 + lane] = m[qc];
      Lml[wv][qc * 16 + lane] = lsum[qc];
    }
  }
  // phase 1: hi waves park partial O^T; combine hi rows
  if (grp == 0) {
#pragma unroll
    for (int hf = 0; hf < 8; ++hf)
#pragma unroll
      for (int qc = 0; qc < 2; ++qc)
        *(f32x4*)&OC[wv][(qc * 16 + cg) * OCW + hf * 16 + rg * 4] = o[hf][qc];
  }
  __syncthreads();
  {
    const int qb = (63 - p) << 5;
    for (int i = tid; i < 32 * 128; i += 512) {
      int row = i >> 7, col = i & 127;
      float ms = fmaxf(fmaxf(Mml[0][row], Mml[1][row]), fmaxf(Mml[2][row], Mml[3][row]));
      float accv = 0.f, lacc = 0.f;
#pragma unroll
      for (int w = 0; w < 4; ++w) {
        float sc = exp2f(Mml[w][row] - ms);
        lacc += sc * Lml[w][row];
        accv += sc * OC[w][row * OCW + col];
      }
      out[(size_t)(b * T_ + qb + row) * H_ + col] = accv / lacc;
    }
  }
  __syncthreads();
  // phase 2: lo waves park; combine lo rows
  if (grp == 1) {
#pragma unroll
    for (int hf = 0; hf < 8; ++hf)
#pragma unroll
      for (int qc = 0; qc < 2; ++qc)
        *(f32x4*)&OC[wvl][(qc * 16 + cg) * OCW + hf * 16 + rg * 4] = o[hf][qc];
  }
  __syncthreads();
  {
    const int qb = p << 5;
    for (int i = tid; i < 32 * 128; i += 512) {
      int row = i >> 7, col = i & 127;
      float ms = fmaxf(fmaxf(Mml[4][row], Mml[5][row]), fmaxf(Mml[6][row], Mml[7][row]));
      float accv = 0.f, lacc = 0.f;
#pragma unroll
      for (int w = 0; w < 4; ++w) {
        float sc = exp2f(Mml[4 + w][row] - ms);
        lacc += sc * Lml[4 + w][row];
        accv += sc * OC[w][row * OCW + col];
      }
      out[(size_t)(b * T_ + qb + row) * H_ + col] = accv / lacc;
    }
  }
}

extern "C" void kernel_launch(void* const* d_in, const int* in_sizes, int n_in,
                              void* d_out, int out_size, void* d_ws, size_t ws_size,
                              hipStream_t stream) {
  const float* x  = (const float*)d_in[0];
  const float* Wq = (const float*)d_in[1];
  const float* Wk = (const float*)d_in[2];
  const float* Wv = (const float*)d_in[3];
  float* out = (float*)d_out;
  char* ws = (char*)d_ws;

  short* Wtf = (short*)(ws);                         // 768 KB
  short* Qf  = (short*)(ws + ((size_t)1 << 20));     // 4 MB
  short* Kf  = (short*)(ws + ((size_t)5 << 20));     // 4 MB
  short* Vf  = (short*)(ws + ((size_t)9 << 20));     // 4 MB  (total 13 MB)

  prep_wt<<<dim3(48), dim3(256), 0, stream>>>(Wq, Wk, Wv, Wtf);
  proj<<<dim3(512), dim3(256), 0, stream>>>(x, Wtf, Qf, Kf, Vf);
  attn<<<dim3(256), dim3(512), 0, stream>>>(Qf, Kf, Vf, out);
}

// Round 16
// 93.282 us; speedup vs baseline: 1.0007x; 1.0007x over previous
//
#include <hip/hip_runtime.h>

// Fused causal attention head: B=8, T=2048, C=1024, H=128 (fp32 in/out).
//   q,k,v = x@W{q,k,v};  out = softmax(tril(q k^T * C^-0.5)) @ v
// All intermediates (Wtf, Qf, Kf, Vf) are MFMA-fragment-major so every hot load
// is a coalesced `base + lane*16B` read (round-6 win).
//   QK-frag layout: frag(t16, k32) = 1KB contiguous;
//     idx(t,h) = ((t>>4)*NK + (h>>5))*512 + ((h>>3)&3)*128 + (t&15)*8 + (h&7)
//   V-frag layout: frag(t16, h16) = 512B contiguous.
// Round-16: round-15's full-V-tile prefetch with the launch-bounds bug fixed.
//   (512,2) on an 8-wave block = 2 waves/EU -> VGPR capped at 128 -> the
//   V prefetch + O accumulator spilled (WRITE_SIZE 42MB vs 8.2MB output).
//   Plain (512) lets the compiler take ~230 VGPR at the same 2-waves/SIMD
//   occupancy attn has had since round 8. V-load latency (24 loads formerly
//   inline in the PV cluster) now hides under LOADK+mask+softmax.
//   proj/prep: byte-identical to round 13 (best total 69.3).
// Workspace (~13 MB): [0,768K) Wtf  [1M,5M) Qf  [5M,9M) Kf  [9M,13M) Vf

#define B_ 8
#define T_ 2048
#define C_ 1024
#define H_ 128

typedef __attribute__((ext_vector_type(4))) float  f32x4;
typedef __attribute__((ext_vector_type(8))) __bf16 bf16x8;
typedef __attribute__((ext_vector_type(4))) __bf16 bf16x4;
typedef __attribute__((ext_vector_type(4))) short  short4v;

#define QSCALE (0.03125f * 1.44269504088896340736f)  // C^-0.5 * log2(e)

static __device__ __forceinline__ short f2bf(float f) {
  union { __bf16 b; short s; } u;
  u.b = (__bf16)f;
  return u.s;
}

static __device__ __forceinline__ unsigned packbf2(float lo, float hi) {
  union { __bf16 b; unsigned short s; } a, c;
  a.b = (__bf16)lo; c.b = (__bf16)hi;
  return (unsigned)a.s | ((unsigned)c.s << 16);
}

// fragment-major index helpers
static __device__ __forceinline__ size_t qk_idx(int t, int h, int nk) {
  return ((size_t)((t >> 4) * nk + (h >> 5)) << 9) + (((h >> 3) & 3) << 7)
       + ((t & 15) << 3) + (h & 7);
}
static __device__ __forceinline__ size_t v_idx(int h, int t) {
  return ((size_t)((t >> 4) * 8 + (h >> 4)) << 8) + ((h & 15) << 4) + (t & 15);
}

// D = A(16x16) * B(16x16) + C, bf16, K=16.
static __device__ __forceinline__ f32x4 mfma16(unsigned a0, unsigned a1,
                                               unsigned b0, unsigned b1, f32x4 c) {
#if __has_builtin(__builtin_amdgcn_mfma_f32_16x16x16_bf16)
  union { unsigned u[2]; bf16x4 v; } ua, ub;
  ua.u[0] = a0; ua.u[1] = a1; ub.u[0] = b0; ub.u[1] = b1;
  return __builtin_amdgcn_mfma_f32_16x16x16_bf16(ua.v, ub.v, c, 0, 0, 0);
#elif __has_builtin(__builtin_amdgcn_mfma_f32_16x16x16bf16_1k)
  union { unsigned u[2]; short4v v; } ua, ub;
  ua.u[0] = a0; ua.u[1] = a1; ub.u[0] = b0; ub.u[1] = b1;
  return __builtin_amdgcn_mfma_f32_16x16x16bf16_1k(ua.v, ub.v, c, 0, 0, 0);
#else
  union { unsigned u[2]; short4v v; } ua, ub;
  ua.u[0] = a0; ua.u[1] = a1; ub.u[0] = b0; ub.u[1] = b1;
  f32x4 d = c;
  asm volatile("v_mfma_f32_16x16x16_bf16 %0, %1, %2, %0"
               : "+v"(d) : "v"(ua.v), "v"(ub.v));
  return d;
#endif
}

// ---------------- prep: Wtf frag-major; Wq pre-scaled by QSCALE -------------------
__global__ void prep_wt(const float* __restrict__ Wq, const float* __restrict__ Wk,
                        const float* __restrict__ Wv, short* __restrict__ Wtf) {
  __shared__ float L[64 * 129];
  const int mtx = blockIdx.x >> 4, kc = blockIdx.x & 15;
  const int k0 = kc * 64;
  const float* W = (mtx == 0) ? Wq : (mtx == 1 ? Wk : Wv);
  const float s = (mtx == 0) ? QSCALE : 1.0f;
  for (int i = threadIdx.x; i < 64 * 128; i += 256) {
    int kk = i >> 7, c = i & 127;
    L[kk * 129 + c] = W[(size_t)(k0 + kk) * H_ + c] * s;
  }
  __syncthreads();
  for (int i = threadIdx.x; i < 128 * 64; i += 256) {
    int n = i >> 6, kk = i & 63;
    Wtf[qk_idx(mtx * 128 + n, k0 + kk, 32)] = f2bf(L[kk * 129 + n]);
  }
}

// ---------------- proj: BM=64 x BN=192, BK=128, raw-barrier pipeline, grid 512 ----
// (round-13 structure, unchanged)
__global__ __launch_bounds__(256) void proj(const float* __restrict__ x,
                                            const short* __restrict__ Wtf,
                                            short* __restrict__ Qf,
                                            short* __restrict__ Kf,
                                            short* __restrict__ Vf) {
  __shared__ __align__(16) short At[2][64 * 128];  // bf16 tiles, 16 KB each
  const int tid = threadIdx.x, lane = tid & 63, wv = tid >> 6;
  const int cg = lane & 15, rg = lane >> 4;
  const int lane8 = lane << 3;
  const int g = (blockIdx.x & 7) * 64 + (blockIdx.x >> 3);
  const int mb = g >> 1, bn = g & 1;
  const int m0 = mb * 64;
  const int nfrag0 = bn * 12 + wv * 3;
  const float* xblk = x + (size_t)m0 * C_;

  f32x4 acc[4][3];
#pragma unroll
  for (int i = 0; i < 4; ++i)
#pragma unroll
    for (int j = 0; j < 3; ++j) {
      f32x4 z = {0.f, 0.f, 0.f, 0.f};
      acc[i][j] = z;
    }

  f32x4 ldr[4][2];  // staging regs: 8 dwordx4 loads/thread (one kt tile)

#define PLOAD(kt)                                                              \
  { _Pragma("unroll") for (int it = 0; it < 4; ++it) {                         \
      int ls = it * 256 + tid; int r = ls >> 4, sc = ls & 15;                  \
      const float* p = xblk + (size_t)r * C_ + (kt) * 128 + sc * 8;            \
      ldr[it][0] = *(const f32x4*)p; ldr[it][1] = *(const f32x4*)(p + 4);      \
  } }

#define PWRITE(bf)                                                             \
  { _Pragma("unroll") for (int it = 0; it < 4; ++it) {                         \
      int ls = it * 256 + tid; int r = ls >> 4, sc = ls & 15;                  \
      bf16x8 tv;                                                               \
      tv[0] = (__bf16)ldr[it][0][0]; tv[1] = (__bf16)ldr[it][0][1];            \
      tv[2] = (__bf16)ldr[it][0][2]; tv[3] = (__bf16)ldr[it][0][3];            \
      tv[4] = (__bf16)ldr[it][1][0]; tv[5] = (__bf16)ldr[it][1][1];            \
      tv[6] = (__bf16)ldr[it][1][2]; tv[7] = (__bf16)ldr[it][1][3];            \
      *(bf16x8*)&At[bf][r * 128 + ((sc ^ (r & 7)) << 3)] = tv;                 \
  } }

  // raw barrier: ds-writes visible (lgkmcnt 0) but vector loads STAY in flight
#define RAWBAR()                                                               \
  { asm volatile("s_waitcnt lgkmcnt(0)" ::: "memory");                         \
    __builtin_amdgcn_sched_barrier(0);                                         \
    __builtin_amdgcn_s_barrier(); }

  PLOAD(0);
  PWRITE(0);
  PLOAD(1);
  RAWBAR();

  for (int kt = 0; kt < 8; ++kt) {
    const int cur = kt & 1;

#pragma unroll
    for (int ks = 0; ks < 4; ++ks) {
      bf16x8 af[4];
#pragma unroll
      for (int fm = 0; fm < 4; ++fm) {
        int r = fm * 16 + cg;
        int slot = (ks * 4 + rg) ^ (r & 7);
        af[fm] = *(const bf16x8*)&At[cur][r * 128 + (slot << 3)];
      }
#pragma unroll
      for (int nf = 0; nf < 3; ++nf) {
        bf16x8 bfr = *(const bf16x8*)&Wtf[((size_t)((nfrag0 + nf) * 32 + kt * 4 + ks) << 9) + lane8];
#pragma unroll
        for (int fm = 0; fm < 4; ++fm)
          acc[fm][nf] = __builtin_amdgcn_mfma_f32_16x16x32_bf16(af[fm], bfr, acc[fm][nf], 0, 0, 0);
      }
    }
    if (kt < 7) PWRITE(cur ^ 1);
    if (kt < 6) PLOAD(kt + 2);
    RAWBAR();
  }
#undef PLOAD
#undef PWRITE
#undef RAWBAR

  // epilogue: D frag row=(lane>>4)*4+r, col=lane&15; scatter into frag layouts
#pragma unroll
  for (int fm = 0; fm < 4; ++fm) {
#pragma unroll
    for (int nf = 0; nf < 3; ++nf) {
      int n = (nfrag0 + nf) * 16 + cg;
      int rowm = m0 + fm * 16 + rg * 4;
      size_t boff = (size_t)(rowm >> 11) << 18;   // batch * 2048*128
      f32x4 v = acc[fm][nf];
      if (n < 128) {
#pragma unroll
        for (int r = 0; r < 4; ++r)
          Qf[boff + qk_idx((rowm + r) & 2047, n, 4)] = f2bf(v[r]);
      } else if (n < 256) {
#pragma unroll
        for (int r = 0; r < 4; ++r)
          Kf[boff + qk_idx((rowm + r) & 2047, n - 128, 4)] = f2bf(v[r]);
      } else {
#pragma unroll
        for (int r = 0; r < 4; ++r)
          Vf[boff + v_idx(n - 256, (rowm + r) & 2047)] = f2bf(v[r]);
      }
    }
  }
}

// ---------------- attn: paired q-groups, per-SIMD balanced, full-V prefetch -------
// grid 256: b = bid&7 (XCD-local K/V), p = bid>>3 in [0,32).
// 8 waves: wv 0-3 -> qg = 63-p (kv-split 4), wv 4-7 -> qg = p (kv-split 4).
// Plain launch_bounds(512): no min-wave VGPR cap (round-15 lesson).
#define OCW 132  // 128 + 4 pad
__global__ __launch_bounds__(512) void attn(const short* __restrict__ Qf,
                                            const short* __restrict__ Kf,
                                            const short* __restrict__ Vf,
                                            float* __restrict__ out) {
  __shared__ __align__(16) float OC[4][32 * OCW];   // 67.6 KB, reused hi then lo
  __shared__ float Mml[8][32], Lml[8][32];
  const int tid = threadIdx.x, lane = tid & 63, wv = tid >> 6;
  const int cg = lane & 15, rg = lane >> 4;
  const int lane8 = lane << 3;
  const int bid = blockIdx.x;
  const int b = bid & 7;
  const int p = bid >> 3;                // 0..31
  const int grp = wv >> 2;               // 0 = hi group, 1 = lo group
  const int wvl = wv & 3;                // kv-split index within group
  const int qg = grp ? p : (63 - p);
  const int q0 = qg << 5;
  const int NT = (q0 + 95) >> 6;         // ceil((q0+32)/64) kv-tiles of 64
  const int SPW = (NT + 3) >> 2;
  const int t0 = wvl * SPW;
  const int t1 = (t0 + SPW < NT) ? (t0 + SPW) : NT;

  const short* Qp = Qf + ((size_t)b << 18);
  const short* Kp = Kf + ((size_t)b << 18);
  const short* Vp = Vf + ((size_t)b << 18);
  const float NEG_INF = -__builtin_inff();

  // Q frags (B-operand for swapped QK^T): coalesced frag reads
  bf16x8 qf[2][4];
#pragma unroll
  for (int qc = 0; qc < 2; ++qc)
#pragma unroll
    for (int ks = 0; ks < 4; ++ks)
      qf[qc][ks] = *(const bf16x8*)&Qp[((size_t)(((q0 >> 4) + qc) * 4 + ks) << 9) + lane8];

  f32x4 o[8][2];                         // O^T: o[hf][qc][r] = O[q][h=hf*16+rg*4+r]
#pragma unroll
  for (int f = 0; f < 8; ++f)
#pragma unroll
    for (int qc = 0; qc < 2; ++qc) { f32x4 z = {0.f, 0.f, 0.f, 0.f}; o[f][qc] = z; }
  float m[2] = {NEG_INF, NEG_INF}, lsum[2] = {0.0f, 0.0f};

  bf16x8 kf[4][4];
#define LOADK(t_)                                                              \
  { const short* ktp = Kp + (size_t)(t_) * 8192;                               \
    _Pragma("unroll") for (int nf_ = 0; nf_ < 4; ++nf_)                        \
    _Pragma("unroll") for (int ks_ = 0; ks_ < 4; ++ks_)                        \
      kf[nf_][ks_] = *(const bf16x8*)&ktp[((nf_ * 4 + ks_) << 9) + lane8]; }

  if (t0 < t1) LOADK(t0);

  for (int t = t0; t < t1; ++t) {
    const int kv0 = t * 64;
    const short* vtile = Vp + (size_t)t * 8192;

    f32x4 s[4][2];
#pragma unroll
    for (int nf = 0; nf < 4; ++nf)
#pragma unroll
      for (int qc = 0; qc < 2; ++qc) { f32x4 z = {0.f, 0.f, 0.f, 0.f}; s[nf][qc] = z; }

    // S^T = K Q^T
    __builtin_amdgcn_s_setprio(1);
#pragma unroll
    for (int nf = 0; nf < 4; ++nf)
#pragma unroll
      for (int ks = 0; ks < 4; ++ks) {
        s[nf][0] = __builtin_amdgcn_mfma_f32_16x16x32_bf16(kf[nf][ks], qf[0][ks], s[nf][0], 0, 0, 0);
        s[nf][1] = __builtin_amdgcn_mfma_f32_16x16x32_bf16(kf[nf][ks], qf[1][ks], s[nf][1], 0, 0, 0);
      }
    __builtin_amdgcn_s_setprio(0);

    // FULL V-tile prefetch (32 x 8B): latency hides under LOADK+mask+softmax
    unsigned va[4][8], vb[4][8];
#pragma unroll
    for (int nf = 0; nf < 4; ++nf)
#pragma unroll
      for (int hf = 0; hf < 8; ++hf) {
        const unsigned* vp = (const unsigned*)&vtile[((nf * 8 + hf) << 8) + (cg << 4) + (rg << 2)];
        va[nf][hf] = vp[0]; vb[nf][hf] = vp[1];
      }

    // K software-pipeline: next tile into the same kf regs
    if (t + 1 < t1) LOADK(t + 1);

    // causal mask (only the globally-last tile straddles the diagonal)
    if (t == NT - 1) {
#pragma unroll
      for (int nf = 0; nf < 4; ++nf)
#pragma unroll
        for (int qc = 0; qc < 2; ++qc)
#pragma unroll
          for (int r = 0; r < 4; ++r)
            if (kv0 + nf * 16 + rg * 4 + r > q0 + qc * 16 + cg) s[nf][qc][r] = NEG_INF;
    }

    // online softmax (exp2 domain) with T13 defer-max
    unsigned pk[4][2][2];
#pragma unroll
    for (int qc = 0; qc < 2; ++qc) {
      float pm = s[0][qc][0];
#pragma unroll
      for (int nf = 0; nf < 4; ++nf)
#pragma unroll
        for (int r = 0; r < 4; ++r) pm = fmaxf(pm, s[nf][qc][r]);
      pm = fmaxf(pm, __shfl_xor(pm, 16));
      pm = fmaxf(pm, __shfl_xor(pm, 32));   // full row max
      if (!__all(pm <= m[qc] + 8.0f)) {     // T13: rescale only on real growth
        float mn = fmaxf(m[qc], pm);
        float sf = exp2f(m[qc] - mn);       // first tile: exp2(-inf) = 0
        m[qc] = mn;
        lsum[qc] *= sf;
#pragma unroll
        for (int f = 0; f < 8; ++f)
#pragma unroll
          for (int r = 0; r < 4; ++r) o[f][qc][r] *= sf;
      }
      float mq = m[qc];
#pragma unroll
      for (int nf = 0; nf < 4; ++nf) {
        float p0 = exp2f(s[nf][qc][0] - mq), p1 = exp2f(s[nf][qc][1] - mq);
        float p2 = exp2f(s[nf][qc][2] - mq), p3 = exp2f(s[nf][qc][3] - mq);
        lsum[qc] += (p0 + p1) + (p2 + p3);
        pk[nf][qc][0] = packbf2(p0, p1);
        pk[nf][qc][1] = packbf2(p2, p3);
      }
    }

    // O^T += V^T P^T via 16x16x16 — all operands in registers
    __builtin_amdgcn_s_setprio(1);
#pragma unroll
    for (int nf = 0; nf < 4; ++nf) {
      const unsigned b00 = pk[nf][0][0], b01 = pk[nf][0][1];
      const unsigned b10 = pk[nf][1][0], b11 = pk[nf][1][1];
#pragma unroll
      for (int hf = 0; hf < 8; ++hf) {
        o[hf][0] = mfma16(va[nf][hf], vb[nf][hf], b00, b01, o[hf][0]);
        o[hf][1] = mfma16(va[nf][hf], vb[nf][hf], b10, b11, o[hf][1]);
      }
    }
    __builtin_amdgcn_s_setprio(0);
  }
#undef LOADK

  // reduce l across rg groups (same q); m already row-uniform
#pragma unroll
  for (int qc = 0; qc < 2; ++qc) {
    lsum[qc] += __shfl_xor(lsum[qc], 16);
    lsum[qc] += __shfl_xor(lsum[qc], 32);
  }
  if (lane < 16) {
#pragma unroll
    for (int qc = 0; qc < 2; ++qc) {
      Mml[wv][qc * 16 + lane] = m[qc];
      Lml[wv][qc * 16 + lane] = lsum[qc];
    }
  }
  // phase 1: hi waves park partial O^T; combine hi rows
  if (grp == 0) {
#pragma unroll
    for (int hf = 0; hf < 8; ++hf)
#pragma unroll
      for (int qc = 0; qc < 2; ++qc)
        *(f32x4*)&OC[wv][(qc * 16 + cg) * OCW + hf * 16 + rg * 4] = o[hf][qc];
  }
  __syncthreads();
  {
    const int qb = (63 - p) << 5;
    for (int i = tid; i < 32 * 128; i += 512) {
      int row = i >> 7, col = i & 127;
      float ms = fmaxf(fmaxf(Mml[0][row], Mml[1][row]), fmaxf(Mml[2][row], Mml[3][row]));
      float accv = 0.f, lacc = 0.f;
#pragma unroll
      for (int w = 0; w < 4; ++w) {
        float sc = exp2f(Mml[w][row] - ms);
        lacc += sc * Lml[w][row];
        accv += sc * OC[w][row * OCW + col];
      }
      out[(size_t)(b * T_ + qb + row) * H_ + col] = accv / lacc;
    }
  }
  __syncthreads();
  // phase 2: lo waves park; combine lo rows
  if (grp == 1) {
#pragma unroll
    for (int hf = 0; hf < 8; ++hf)
#pragma unroll
      for (int qc = 0; qc < 2; ++qc)
        *(f32x4*)&OC[wvl][(qc * 16 + cg) * OCW + hf * 16 + rg * 4] = o[hf][qc];
  }
  __syncthreads();
  {
    const int qb = p << 5;
    for (int i = tid; i < 32 * 128; i += 512) {
      int row = i >> 7, col = i & 127;
      float ms = fmaxf(fmaxf(Mml[4][row], Mml[5][row]), fmaxf(Mml[6][row], Mml[7][row]));
      float accv = 0.f, lacc = 0.f;
#pragma unroll
      for (int w = 0; w < 4; ++w) {
        float sc = exp2f(Mml[4 + w][row] - ms);
        lacc += sc * Lml[4 + w][row];
        accv += sc * OC[w][row * OCW + col];
      }
      out[(size_t)(b * T_ + qb + row) * H_ + col] = accv / lacc;
    }
  }
}

extern "C" void kernel_launch(void* const* d_in, const int* in_sizes, int n_in,
                              void* d_out, int out_size, void* d_ws, size_t ws_size,
                              hipStream_t stream) {
  const float* x  = (const float*)d_in[0];
  const float* Wq = (const float*)d_in[1];
  const float* Wk = (const float*)d_in[2];
  const float* Wv = (const float*)d_in[3];
  float* out = (float*)d_out;
  char* ws = (char*)d_ws;

  short* Wtf = (short*)(ws);                         // 768 KB
  short* Qf  = (short*)(ws + ((size_t)1 << 20));     // 4 MB
  short* Kf  = (short*)(ws + ((size_t)5 << 20));     // 4 MB
  short* Vf  = (short*)(ws + ((size_t)9 << 20));     // 4 MB  (total 13 MB)

  prep_wt<<<dim3(48), dim3(256), 0, stream>>>(Wq, Wk, Wv, Wtf);
  proj<<<dim3(512), dim3(256), 0, stream>>>(x, Wtf, Qf, Kf, Vf);
  attn<<<dim3(256), dim3(512), 0, stream>>>(Qf, Kf, Vf, out);
}

// Round 17
// 69.018 us; speedup vs baseline: 1.3526x; 1.3515x over previous
//
#include <hip/hip_runtime.h>

// Fused causal attention head: B=8, T=2048, C=1024, H=128 (fp32 in/out).
//   q,k,v = x@W{q,k,v};  out = softmax(tril(q k^T * C^-0.5)) @ v
// All intermediates (Wtf, Qf, Kf, Vf) are MFMA-fragment-major so every hot load
// is a coalesced `base + lane*16B` read (round-6 win).
//   QK-frag layout: frag(t16, k32) = 1KB contiguous;
//     idx(t,h) = ((t>>4)*NK + (h>>5))*512 + ((h>>3)&3)*128 + (t&15)*8 + (h&7)
//   V-frag layout: frag(t16, h16) = 512B contiguous.
// Round-17: exact revert to round-13 (measured best, 69.28 us).
//   - proj: BM=64 x BN=192, BK=128, reg-staged bf16 LDS dbuf, raw s_barrier
//     (lgkmcnt-only) so prefetch loads stay in flight. ~41 us — pinned across
//     8 structural knobs (rounds 9-14); latency-bound at this skinny shape.
//   - attn: 8-wave hi/lo-paired q-groups (per-SIMD balanced), swapped QK^T,
//     in-register P, K reg pipeline, V-nf0 prefetch, T13 defer-max. ~25 us.
//     Full-V prefetch is impossible: hipcc pins 512-thread blocks at 128 VGPR
//     (rounds 15/16: spills, WRITE_SIZE 42 MB).
// Workspace (~13 MB): [0,768K) Wtf  [1M,5M) Qf  [5M,9M) Kf  [9M,13M) Vf

#define B_ 8
#define T_ 2048
#define C_ 1024
#define H_ 128

typedef __attribute__((ext_vector_type(4))) float  f32x4;
typedef __attribute__((ext_vector_type(8))) __bf16 bf16x8;
typedef __attribute__((ext_vector_type(4))) __bf16 bf16x4;
typedef __attribute__((ext_vector_type(4))) short  short4v;

#define QSCALE (0.03125f * 1.44269504088896340736f)  // C^-0.5 * log2(e)

static __device__ __forceinline__ short f2bf(float f) {
  union { __bf16 b; short s; } u;
  u.b = (__bf16)f;
  return u.s;
}

static __device__ __forceinline__ unsigned packbf2(float lo, float hi) {
  union { __bf16 b; unsigned short s; } a, c;
  a.b = (__bf16)lo; c.b = (__bf16)hi;
  return (unsigned)a.s | ((unsigned)c.s << 16);
}

// fragment-major index helpers
static __device__ __forceinline__ size_t qk_idx(int t, int h, int nk) {
  return ((size_t)((t >> 4) * nk + (h >> 5)) << 9) + (((h >> 3) & 3) << 7)
       + ((t & 15) << 3) + (h & 7);
}
static __device__ __forceinline__ size_t v_idx(int h, int t) {
  return ((size_t)((t >> 4) * 8 + (h >> 4)) << 8) + ((h & 15) << 4) + (t & 15);
}

// D = A(16x16) * B(16x16) + C, bf16, K=16.
static __device__ __forceinline__ f32x4 mfma16(unsigned a0, unsigned a1,
                                               unsigned b0, unsigned b1, f32x4 c) {
#if __has_builtin(__builtin_amdgcn_mfma_f32_16x16x16_bf16)
  union { unsigned u[2]; bf16x4 v; } ua, ub;
  ua.u[0] = a0; ua.u[1] = a1; ub.u[0] = b0; ub.u[1] = b1;
  return __builtin_amdgcn_mfma_f32_16x16x16_bf16(ua.v, ub.v, c, 0, 0, 0);
#elif __has_builtin(__builtin_amdgcn_mfma_f32_16x16x16bf16_1k)
  union { unsigned u[2]; short4v v; } ua, ub;
  ua.u[0] = a0; ua.u[1] = a1; ub.u[0] = b0; ub.u[1] = b1;
  return __builtin_amdgcn_mfma_f32_16x16x16bf16_1k(ua.v, ub.v, c, 0, 0, 0);
#else
  union { unsigned u[2]; short4v v; } ua, ub;
  ua.u[0] = a0; ua.u[1] = a1; ub.u[0] = b0; ub.u[1] = b1;
  f32x4 d = c;
  asm volatile("v_mfma_f32_16x16x16_bf16 %0, %1, %2, %0"
               : "+v"(d) : "v"(ua.v), "v"(ub.v));
  return d;
#endif
}

// ---------------- prep: Wtf frag-major; Wq pre-scaled by QSCALE -------------------
__global__ void prep_wt(const float* __restrict__ Wq, const float* __restrict__ Wk,
                        const float* __restrict__ Wv, short* __restrict__ Wtf) {
  __shared__ float L[64 * 129];
  const int mtx = blockIdx.x >> 4, kc = blockIdx.x & 15;
  const int k0 = kc * 64;
  const float* W = (mtx == 0) ? Wq : (mtx == 1 ? Wk : Wv);
  const float s = (mtx == 0) ? QSCALE : 1.0f;
  for (int i = threadIdx.x; i < 64 * 128; i += 256) {
    int kk = i >> 7, c = i & 127;
    L[kk * 129 + c] = W[(size_t)(k0 + kk) * H_ + c] * s;
  }
  __syncthreads();
  for (int i = threadIdx.x; i < 128 * 64; i += 256) {
    int n = i >> 6, kk = i & 63;
    Wtf[qk_idx(mtx * 128 + n, k0 + kk, 32)] = f2bf(L[kk * 129 + n]);
  }
}

// ---------------- proj: BM=64 x BN=192, BK=128, raw-barrier pipeline, grid 512 ----
__global__ __launch_bounds__(256) void proj(const float* __restrict__ x,
                                            const short* __restrict__ Wtf,
                                            short* __restrict__ Qf,
                                            short* __restrict__ Kf,
                                            short* __restrict__ Vf) {
  __shared__ __align__(16) short At[2][64 * 128];  // bf16 tiles, 16 KB each
  const int tid = threadIdx.x, lane = tid & 63, wv = tid >> 6;
  const int cg = lane & 15, rg = lane >> 4;
  const int lane8 = lane << 3;
  const int g = (blockIdx.x & 7) * 64 + (blockIdx.x >> 3);
  const int mb = g >> 1, bn = g & 1;
  const int m0 = mb * 64;
  const int nfrag0 = bn * 12 + wv * 3;
  const float* xblk = x + (size_t)m0 * C_;

  f32x4 acc[4][3];
#pragma unroll
  for (int i = 0; i < 4; ++i)
#pragma unroll
    for (int j = 0; j < 3; ++j) {
      f32x4 z = {0.f, 0.f, 0.f, 0.f};
      acc[i][j] = z;
    }

  f32x4 ldr[4][2];  // staging regs: 8 dwordx4 loads/thread (one kt tile)

#define PLOAD(kt)                                                              \
  { _Pragma("unroll") for (int it = 0; it < 4; ++it) {                         \
      int ls = it * 256 + tid; int r = ls >> 4, sc = ls & 15;                  \
      const float* p = xblk + (size_t)r * C_ + (kt) * 128 + sc * 8;            \
      ldr[it][0] = *(const f32x4*)p; ldr[it][1] = *(const f32x4*)(p + 4);      \
  } }

#define PWRITE(bf)                                                             \
  { _Pragma("unroll") for (int it = 0; it < 4; ++it) {                         \
      int ls = it * 256 + tid; int r = ls >> 4, sc = ls & 15;                  \
      bf16x8 tv;                                                               \
      tv[0] = (__bf16)ldr[it][0][0]; tv[1] = (__bf16)ldr[it][0][1];            \
      tv[2] = (__bf16)ldr[it][0][2]; tv[3] = (__bf16)ldr[it][0][3];            \
      tv[4] = (__bf16)ldr[it][1][0]; tv[5] = (__bf16)ldr[it][1][1];            \
      tv[6] = (__bf16)ldr[it][1][2]; tv[7] = (__bf16)ldr[it][1][3];            \
      *(bf16x8*)&At[bf][r * 128 + ((sc ^ (r & 7)) << 3)] = tv;                 \
  } }

  // raw barrier: ds-writes visible (lgkmcnt 0) but vector loads STAY in flight
#define RAWBAR()                                                               \
  { asm volatile("s_waitcnt lgkmcnt(0)" ::: "memory");                         \
    __builtin_amdgcn_sched_barrier(0);                                         \
    __builtin_amdgcn_s_barrier(); }

  PLOAD(0);
  PWRITE(0);
  PLOAD(1);
  RAWBAR();

  for (int kt = 0; kt < 8; ++kt) {
    const int cur = kt & 1;

#pragma unroll
    for (int ks = 0; ks < 4; ++ks) {
      bf16x8 af[4];
#pragma unroll
      for (int fm = 0; fm < 4; ++fm) {
        int r = fm * 16 + cg;
        int slot = (ks * 4 + rg) ^ (r & 7);
        af[fm] = *(const bf16x8*)&At[cur][r * 128 + (slot << 3)];
      }
#pragma unroll
      for (int nf = 0; nf < 3; ++nf) {
        bf16x8 bfr = *(const bf16x8*)&Wtf[((size_t)((nfrag0 + nf) * 32 + kt * 4 + ks) << 9) + lane8];
#pragma unroll
        for (int fm = 0; fm < 4; ++fm)
          acc[fm][nf] = __builtin_amdgcn_mfma_f32_16x16x32_bf16(af[fm], bfr, acc[fm][nf], 0, 0, 0);
      }
    }
    if (kt < 7) PWRITE(cur ^ 1);
    if (kt < 6) PLOAD(kt + 2);
    RAWBAR();
  }
#undef PLOAD
#undef PWRITE
#undef RAWBAR

  // epilogue: D frag row=(lane>>4)*4+r, col=lane&15; scatter into frag layouts
#pragma unroll
  for (int fm = 0; fm < 4; ++fm) {
#pragma unroll
    for (int nf = 0; nf < 3; ++nf) {
      int n = (nfrag0 + nf) * 16 + cg;
      int rowm = m0 + fm * 16 + rg * 4;
      size_t boff = (size_t)(rowm >> 11) << 18;   // batch * 2048*128
      f32x4 v = acc[fm][nf];
      if (n < 128) {
#pragma unroll
        for (int r = 0; r < 4; ++r)
          Qf[boff + qk_idx((rowm + r) & 2047, n, 4)] = f2bf(v[r]);
      } else if (n < 256) {
#pragma unroll
        for (int r = 0; r < 4; ++r)
          Kf[boff + qk_idx((rowm + r) & 2047, n - 128, 4)] = f2bf(v[r]);
      } else {
#pragma unroll
        for (int r = 0; r < 4; ++r)
          Vf[boff + v_idx(n - 256, (rowm + r) & 2047)] = f2bf(v[r]);
      }
    }
  }
}

// ---------------- attn: paired q-groups, per-SIMD balanced ------------------------
// grid 256: b = bid&7 (XCD-local K/V), p = bid>>3 in [0,32).
// 8 waves: wv 0-3 -> qg = 63-p (kv-split 4), wv 4-7 -> qg = p (kv-split 4).
// Wave->SIMD round-robin gives each SIMD one hi + one lo wave: uniform load.
#define OCW 132  // 128 + 4 pad
__global__ __launch_bounds__(512) void attn(const short* __restrict__ Qf,
                                            const short* __restrict__ Kf,
                                            const short* __restrict__ Vf,
                                            float* __restrict__ out) {
  __shared__ __align__(16) float OC[4][32 * OCW];   // 67.6 KB, reused hi then lo
  __shared__ float Mml[8][32], Lml[8][32];
  const int tid = threadIdx.x, lane = tid & 63, wv = tid >> 6;
  const int cg = lane & 15, rg = lane >> 4;
  const int lane8 = lane << 3;
  const int bid = blockIdx.x;
  const int b = bid & 7;
  const int p = bid >> 3;                // 0..31
  const int grp = wv >> 2;               // 0 = hi group, 1 = lo group
  const int wvl = wv & 3;                // kv-split index within group
  const int qg = grp ? p : (63 - p);
  const int q0 = qg << 5;
  const int NT = (q0 + 95) >> 6;         // ceil((q0+32)/64) kv-tiles of 64
  const int SPW = (NT + 3) >> 2;
  const int t0 = wvl * SPW;
  const int t1 = (t0 + SPW < NT) ? (t0 + SPW) : NT;

  const short* Qp = Qf + ((size_t)b << 18);
  const short* Kp = Kf + ((size_t)b << 18);
  const short* Vp = Vf + ((size_t)b << 18);
  const float NEG_INF = -__builtin_inff();

  // Q frags (B-operand for swapped QK^T): coalesced frag reads
  bf16x8 qf[2][4];
#pragma unroll
  for (int qc = 0; qc < 2; ++qc)
#pragma unroll
    for (int ks = 0; ks < 4; ++ks)
      qf[qc][ks] = *(const bf16x8*)&Qp[((size_t)(((q0 >> 4) + qc) * 4 + ks) << 9) + lane8];

  f32x4 o[8][2];                         // O^T: o[hf][qc][r] = O[q][h=hf*16+rg*4+r]
#pragma unroll
  for (int f = 0; f < 8; ++f)
#pragma unroll
    for (int qc = 0; qc < 2; ++qc) { f32x4 z = {0.f, 0.f, 0.f, 0.f}; o[f][qc] = z; }
  float m[2] = {NEG_INF, NEG_INF}, lsum[2] = {0.0f, 0.0f};

  bf16x8 kf[4][4];
#define LOADK(t_)                                                              \
  { const short* ktp = Kp + (size_t)(t_) * 8192;                               \
    _Pragma("unroll") for (int nf_ = 0; nf_ < 4; ++nf_)                        \
    _Pragma("unroll") for (int ks_ = 0; ks_ < 4; ++ks_)                        \
      kf[nf_][ks_] = *(const bf16x8*)&ktp[((nf_ * 4 + ks_) << 9) + lane8]; }

  if (t0 < t1) LOADK(t0);

  for (int t = t0; t < t1; ++t) {
    const int kv0 = t * 64;
    const short* vtile = Vp + (size_t)t * 8192;

    f32x4 s[4][2];
#pragma unroll
    for (int nf = 0; nf < 4; ++nf)
#pragma unroll
      for (int qc = 0; qc < 2; ++qc) { f32x4 z = {0.f, 0.f, 0.f, 0.f}; s[nf][qc] = z; }

    // S^T = K Q^T
    __builtin_amdgcn_s_setprio(1);
#pragma unroll
    for (int nf = 0; nf < 4; ++nf)
#pragma unroll
      for (int ks = 0; ks < 4; ++ks) {
        s[nf][0] = __builtin_amdgcn_mfma_f32_16x16x32_bf16(kf[nf][ks], qf[0][ks], s[nf][0], 0, 0, 0);
        s[nf][1] = __builtin_amdgcn_mfma_f32_16x16x32_bf16(kf[nf][ks], qf[1][ks], s[nf][1], 0, 0, 0);
      }
    __builtin_amdgcn_s_setprio(0);

    // K software-pipeline: next tile into the same kf regs
    if (t + 1 < t1) LOADK(t + 1);

    // V nf0 prefetch
    unsigned v0a[8], v0b[8];
#pragma unroll
    for (int hf = 0; hf < 8; ++hf) {
      const unsigned* vp = (const unsigned*)&vtile[(hf << 8) + (cg << 4) + (rg << 2)];
      v0a[hf] = vp[0]; v0b[hf] = vp[1];
    }

    // causal mask (only the globally-last tile straddles the diagonal)
    if (t == NT - 1) {
#pragma unroll
      for (int nf = 0; nf < 4; ++nf)
#pragma unroll
        for (int qc = 0; qc < 2; ++qc)
#pragma unroll
          for (int r = 0; r < 4; ++r)
            if (kv0 + nf * 16 + rg * 4 + r > q0 + qc * 16 + cg) s[nf][qc][r] = NEG_INF;
    }

    // online softmax (exp2 domain) with T13 defer-max
    unsigned pk[4][2][2];
#pragma unroll
    for (int qc = 0; qc < 2; ++qc) {
      float pm = s[0][qc][0];
#pragma unroll
      for (int nf = 0; nf < 4; ++nf)
#pragma unroll
        for (int r = 0; r < 4; ++r) pm = fmaxf(pm, s[nf][qc][r]);
      pm = fmaxf(pm, __shfl_xor(pm, 16));
      pm = fmaxf(pm, __shfl_xor(pm, 32));   // full row max
      if (!__all(pm <= m[qc] + 8.0f)) {     // T13: rescale only on real growth
        float mn = fmaxf(m[qc], pm);
        float sf = exp2f(m[qc] - mn);       // first tile: exp2(-inf) = 0
        m[qc] = mn;
        lsum[qc] *= sf;
#pragma unroll
        for (int f = 0; f < 8; ++f)
#pragma unroll
          for (int r = 0; r < 4; ++r) o[f][qc][r] *= sf;
      }
      float mq = m[qc];
#pragma unroll
      for (int nf = 0; nf < 4; ++nf) {
        float p0 = exp2f(s[nf][qc][0] - mq), p1 = exp2f(s[nf][qc][1] - mq);
        float p2 = exp2f(s[nf][qc][2] - mq), p3 = exp2f(s[nf][qc][3] - mq);
        lsum[qc] += (p0 + p1) + (p2 + p3);
        pk[nf][qc][0] = packbf2(p0, p1);
        pk[nf][qc][1] = packbf2(p2, p3);
      }
    }

    // O^T += V^T P^T via 16x16x16
    __builtin_amdgcn_s_setprio(1);
#pragma unroll
    for (int hf = 0; hf < 8; ++hf) {
      o[hf][0] = mfma16(v0a[hf], v0b[hf], pk[0][0][0], pk[0][0][1], o[hf][0]);
      o[hf][1] = mfma16(v0a[hf], v0b[hf], pk[0][1][0], pk[0][1][1], o[hf][1]);
    }
#pragma unroll
    for (int nf = 1; nf < 4; ++nf) {
      const unsigned b00 = pk[nf][0][0], b01 = pk[nf][0][1];
      const unsigned b10 = pk[nf][1][0], b11 = pk[nf][1][1];
#pragma unroll
      for (int hf = 0; hf < 8; ++hf) {
        const unsigned* vp = (const unsigned*)&vtile[((nf * 8 + hf) << 8) + (cg << 4) + (rg << 2)];
        unsigned v0 = vp[0], v1 = vp[1];
        o[hf][0] = mfma16(v0, v1, b00, b01, o[hf][0]);
        o[hf][1] = mfma16(v0, v1, b10, b11, o[hf][1]);
      }
    }
    __builtin_amdgcn_s_setprio(0);
  }
#undef LOADK

  // reduce l across rg groups (same q); m already row-uniform
#pragma unroll
  for (int qc = 0; qc < 2; ++qc) {
    lsum[qc] += __shfl_xor(lsum[qc], 16);
    lsum[qc] += __shfl_xor(lsum[qc], 32);
  }
  if (lane < 16) {
#pragma unroll
    for (int qc = 0; qc < 2; ++qc) {
      Mml[wv][qc * 16 + lane] = m[qc];
      Lml[wv][qc * 16 + lane] = lsum[qc];
    }
  }
  // phase 1: hi waves park partial O^T; combine hi rows
  if (grp == 0) {
#pragma unroll
    for (int hf = 0; hf < 8; ++hf)
#pragma unroll
      for (int qc = 0; qc < 2; ++qc)
        *(f32x4*)&OC[wv][(qc * 16 + cg) * OCW + hf * 16 + rg * 4] = o[hf][qc];
  }
  __syncthreads();
  {
    const int qb = (63 - p) << 5;
    for (int i = tid; i < 32 * 128; i += 512) {
      int row = i >> 7, col = i & 127;
      float ms = fmaxf(fmaxf(Mml[0][row], Mml[1][row]), fmaxf(Mml[2][row], Mml[3][row]));
      float accv = 0.f, lacc = 0.f;
#pragma unroll
      for (int w = 0; w < 4; ++w) {
        float sc = exp2f(Mml[w][row] - ms);
        lacc += sc * Lml[w][row];
        accv += sc * OC[w][row * OCW + col];
      }
      out[(size_t)(b * T_ + qb + row) * H_ + col] = accv / lacc;
    }
  }
  __syncthreads();
  // phase 2: lo waves park; combine lo rows
  if (grp == 1) {
#pragma unroll
    for (int hf = 0; hf < 8; ++hf)
#pragma unroll
      for (int qc = 0; qc < 2; ++qc)
        *(f32x4*)&OC[wvl][(qc * 16 + cg) * OCW + hf * 16 + rg * 4] = o[hf][qc];
  }
  __syncthreads();
  {
    const int qb = p << 5;
    for (int i = tid; i < 32 * 128; i += 512) {
      int row = i >> 7, col = i & 127;
      float ms = fmaxf(fmaxf(Mml[4][row], Mml[5][row]), fmaxf(Mml[6][row], Mml[7][row]));
      float accv = 0.f, lacc = 0.f;
#pragma unroll
      for (int w = 0; w < 4; ++w) {
        float sc = exp2f(Mml[4 + w][row] - ms);
        lacc += sc * Lml[4 + w][row];
        accv += sc * OC[w][row * OCW + col];
      }
      out[(size_t)(b * T_ + qb + row) * H_ + col] = accv / lacc;
    }
  }
}

extern "C" void kernel_launch(void* const* d_in, const int* in_sizes, int n_in,
                              void* d_out, int out_size, void* d_ws, size_t ws_size,
                              hipStream_t stream) {
  const float* x  = (const float*)d_in[0];
  const float* Wq = (const float*)d_in[1];
  const float* Wk = (const float*)d_in[2];
  const float* Wv = (const float*)d_in[3];
  float* out = (float*)d_out;
  char* ws = (char*)d_ws;

  short* Wtf = (short*)(ws);                         // 768 KB
  short* Qf  = (short*)(ws + ((size_t)1 << 20));     // 4 MB
  short* Kf  = (short*)(ws + ((size_t)5 << 20));     // 4 MB
  short* Vf  = (short*)(ws + ((size_t)9 << 20));     // 4 MB  (total 13 MB)

  prep_wt<<<dim3(48), dim3(256), 0, stream>>>(Wq, Wk, Wv, Wtf);
  proj<<<dim3(512), dim3(256), 0, stream>>>(x, Wtf, Qf, Kf, Vf);
  attn<<<dim3(256), dim3(512), 0, stream>>>(Qf, Kf, Vf, out);
}